// Round 1
// baseline (1107.835 us; speedup 1.0000x reference)
//
#include <hip/hip_runtime.h>
#include <math.h>

typedef unsigned short u16;
typedef unsigned int u32;
typedef __attribute__((ext_vector_type(8))) short bf16x8;
typedef __attribute__((ext_vector_type(4))) float f32x4;

#define MFMA16(a,b,c) __builtin_amdgcn_mfma_f32_16x16x32_bf16(a,b,c,0,0,0)

__device__ __forceinline__ u16 f2bf(float x){
  union { float f; u32 u; } v; v.f = x;
  u32 u = v.u;
  return (u16)((u + 0x7fffu + ((u>>16)&1u)) >> 16);
}

union B8 { bf16x8 v; u32 u[4]; uint4 q; };

// ---------------- K0: fold BN into bf16 weights ----------------
// alpha = gamma*rsqrt(var+eps); w_eff[o][c] = w[o][c]*alpha[o]*extra
// delta[o] = (beta[o] + (bias[o]-mean[o])*alpha[o]) * extra
__global__ void k0_prep(const float* wm, const float* bias, const float* gamma,
                        const float* beta, const float* mean, const float* var,
                        float extra, u16* wdst, float* ddst)
{
  int t = threadIdx.x;
  if (t < 64){
    float a0 = gamma[t] * rsqrtf(var[t] + 1e-5f);
    ddst[t] = (beta[t] + (bias[t] - mean[t]) * a0) * extra;
  }
  for (int i = t; i < 4096; i += 256){
    int o = i >> 6;
    float a0 = gamma[o] * rsqrtf(var[o] + 1e-5f);
    wdst[i] = f2bf(wm[i] * a0 * extra);
  }
}

// ---------------- K1: QKV projection + BN, writes q,k row-major and v transposed ----
// grid 512 = b(4) x htile(16, 32 rows) x wtile(8, 64 cols); 4 waves, wave = 16-w slab
__global__ __launch_bounds__(256,2)
void k1_qkv(const float* __restrict__ f, const u16* __restrict__ wz,
            const float* __restrict__ dz, u16* __restrict__ q,
            u16* __restrict__ kk_, u16* __restrict__ vt)
{
  int bid = blockIdx.x;
  int b  = bid >> 7;
  int ht = (bid >> 3) & 15;
  int wt = bid & 7;
  int tid = threadIdx.x;
  int wv = tid >> 6, lane = tid & 63;
  int l15 = lane & 15, l4 = lane >> 4;
  int h0 = ht * 32;
  int w0 = wt * 64 + wv * 16;

  // weights for q,k,v as A-fragments (register-resident)
  bf16x8 wa[3][4][2];
  #pragma unroll
  for (int mt=0; mt<3; mt++)
    #pragma unroll
    for (int m=0;m<4;m++)
      #pragma unroll
      for (int ks=0;ks<2;ks++){
        B8 t; t.q = *(const uint4*)(wz + mt*4096 + (m*16+l15)*64 + ks*32 + l4*8);
        wa[mt][m][ks] = t.v;
      }
  f32x4 dv[3][4];
  #pragma unroll
  for (int mt=0;mt<3;mt++)
    #pragma unroll
    for (int m=0;m<4;m++)
      dv[mt][m] = *(const f32x4*)(dz + mt*64 + m*16 + l4*4);

  // per-wave V-transpose staging: [64 o][16 w][8 h], o-stride 136 elems (bank stagger)
  __shared__ u16 vstage[4][8704];
  u16* vs = vstage[wv];

  for (int hh=0; hh<32; hh++){
    int h = h0 + hh;
    // B-fragments: feature[c][w], c = ks*32 + l4*8 + j
    B8 bf[2];
    #pragma unroll
    for (int ks=0;ks<2;ks++){
      #pragma unroll
      for (int jj=0;jj<4;jj++){
        int c0 = ks*32 + l4*8 + jj*2;
        size_t i0 = ((size_t)(b*64 + c0)*512 + h)*512 + w0 + l15;
        float x0 = f[i0];
        float x1 = f[i0 + 262144];
        bf[ks].u[jj] = (u32)f2bf(x0) | ((u32)f2bf(x1) << 16);
      }
    }
    #pragma unroll
    for (int mt=0; mt<3; mt++){
      f32x4 acc[4];
      #pragma unroll
      for (int m=0;m<4;m++) acc[m] = (f32x4){0.f,0.f,0.f,0.f};
      #pragma unroll
      for (int m=0;m<4;m++)
        #pragma unroll
        for (int ks=0;ks<2;ks++)
          acc[m] = MFMA16(wa[mt][m][ks], bf[ks].v, acc[m]);
      #pragma unroll
      for (int m=0;m<4;m++)
        #pragma unroll
        for (int r=0;r<4;r++){
          float val = acc[m][r] + dv[mt][m][r];
          u16 bv = f2bf(val);
          int o = m*16 + l4*4 + r;
          if (mt==0)      q  [((size_t)(b*64+o)*512 + h)*512 + w0 + l15] = bv;
          else if (mt==1) kk_[((size_t)(b*64+o)*512 + h)*512 + w0 + l15] = bv;
          else            vs[o*136 + l15*8 + (hh&7)] = bv;
        }
    }
    if ((hh&7)==7){
      __syncthreads();
      int hb = h - 7;
      #pragma unroll
      for (int r=0;r<16;r++){
        int o = r*4 + l4;
        uint4 d = *(const uint4*)(vs + o*136 + l15*8);
        *(uint4*)(vt + ((size_t)(b*64+o)*512 + (w0+l15))*512 + hb) = d;
      }
      __syncthreads();
    }
  }
}

// ---------------- K2: S = Q K^T (scaled, log2e folded), softmax, write P over q ----
// grid 2048, XCD-swizzled: head = (phys&7)*32 + (phys>>6), ht = (phys>>3)&7
__global__ __launch_bounds__(256,2)
void k2_scores(const u16* q, const u16* kten, u16* p)
{
  int phys = blockIdx.x;
  int head = (phys & 7)*32 + (phys >> 6);
  int ht   = (phys >> 3) & 7;
  int tid = threadIdx.x, wv = tid>>6, lane = tid&63;
  int l15 = lane&15, l4 = lane>>4;
  const u16* qh = q + (size_t)head*262144;
  const u16* kh = kten + (size_t)head*262144;
  int h0 = ht*64 + wv*16;

  __shared__ u16 kt[64*520];   // K-tile [64 g][512 w], rows padded to 520
  f32x4 acc[32];
  #pragma unroll
  for (int i=0;i<32;i++) acc[i] = (f32x4){0.f,0.f,0.f,0.f};

  #pragma unroll
  for (int gt=0; gt<8; gt++){
    __syncthreads();
    #pragma unroll
    for (int rr=0; rr<16; rr++){
      int id = rr*256 + tid;
      int g = id >> 6, cw = id & 63;
      *(uint4*)(kt + g*520 + cw*8) =
        *(const uint4*)(kh + ((size_t)(gt*64+g))*512 + cw*8);
    }
    __syncthreads();
    #pragma unroll
    for (int ks=0; ks<16; ks++){
      B8 a; a.q = *(const uint4*)(qh + (size_t)(h0+l15)*512 + ks*32 + l4*8);
      #pragma unroll
      for (int n=0;n<4;n++){
        B8 bb; bb.q = *(const uint4*)(kt + (n*16+l15)*520 + ks*32 + l4*8);
        acc[gt*4+n] = MFMA16(a.v, bb.v, acc[gt*4+n]);
      }
    }
  }
  // wave-local softmax over g=512 per row (rows: h = h0 + l4*4 + r)
  #pragma unroll
  for (int r=0;r<4;r++){
    float m = acc[0][r];
    #pragma unroll
    for (int f2=1; f2<32; f2++) m = fmaxf(m, acc[f2][r]);
    #pragma unroll
    for (int d=1; d<16; d<<=1) m = fmaxf(m, __shfl_xor(m, d, 64));
    float s = 0.f;
    #pragma unroll
    for (int f2=0; f2<32; f2++){ float e = exp2f(acc[f2][r] - m); s += e; acc[f2][r] = e; }
    #pragma unroll
    for (int d=1; d<16; d<<=1) s += __shfl_xor(s, d, 64);
    float inv = 1.0f / s;
    #pragma unroll
    for (int f2=0; f2<32; f2++) acc[f2][r] *= inv;
  }
  u16* ph = p + (size_t)head*262144;
  #pragma unroll
  for (int f2=0; f2<32; f2++){
    int g = (f2>>2)*64 + (f2&3)*16 + l15;
    #pragma unroll
    for (int r=0;r<4;r++)
      ph[(size_t)(h0 + l4*4 + r)*512 + g] = f2bf(acc[f2][r]);
  }
}

// ---------------- K3: O = P @ V using vT (contiguous B-frags), O over k buffer ----
__global__ __launch_bounds__(256,2)
void k3_pv(const u16* p, const u16* vt, u16* ob)
{
  int phys = blockIdx.x;
  int head = (phys & 7)*32 + (phys >> 6);
  int ht   = (phys >> 3) & 7;
  int tid = threadIdx.x, wv = tid>>6, lane = tid&63;
  int l15 = lane&15, l4 = lane>>4;
  const u16* ph = p + (size_t)head*262144;
  const u16* vh = vt + (size_t)head*262144;   // vh[w*512 + g] = V[g][w]
  int h0 = ht*64 + wv*16;

  __shared__ u16 vtl[512*72];   // [512 w][64 g], rows padded to 72
  f32x4 acc[32];
  #pragma unroll
  for (int i=0;i<32;i++) acc[i] = (f32x4){0.f,0.f,0.f,0.f};

  #pragma unroll
  for (int gt=0; gt<8; gt++){
    __syncthreads();
    #pragma unroll
    for (int rr=0; rr<16; rr++){
      int id = rr*256 + tid;
      int w = id >> 3, cg = id & 7;
      *(uint4*)(vtl + w*72 + cg*8) =
        *(const uint4*)(vh + (size_t)w*512 + gt*64 + cg*8);
    }
    __syncthreads();
    #pragma unroll
    for (int ks=0; ks<2; ks++){
      B8 a; a.q = *(const uint4*)(ph + (size_t)(h0+l15)*512 + gt*64 + ks*32 + l4*8);
      #pragma unroll
      for (int n=0;n<32;n++){
        B8 bb; bb.q = *(const uint4*)(vtl + (n*16+l15)*72 + ks*32 + l4*8);
        acc[n] = MFMA16(a.v, bb.v, acc[n]);
      }
    }
  }
  u16* oh = ob + (size_t)head*262144;
  #pragma unroll
  for (int n=0;n<32;n++)
    #pragma unroll
    for (int r=0;r<4;r++)
      oh[(size_t)(h0 + l4*4 + r)*512 + n*16 + l15] = f2bf(acc[n][r]);
}

// ---------------- K4: out conv + BN + residual, fp32 out ----------------
// grid 4096 = b(4) x h(512) x half(2); wave = 64-w slab
__global__ __launch_bounds__(256,2)
void k4_out(const u16* __restrict__ ob, const u16* __restrict__ wz,
            const float* __restrict__ dz, const float* __restrict__ f,
            float* __restrict__ out)
{
  int bid = blockIdx.x;
  int b = bid >> 10;
  int h = (bid >> 1) & 511;
  int half = bid & 1;
  int tid = threadIdx.x, wv = tid>>6, lane = tid&63;
  int l15 = lane&15, l4 = lane>>4;
  int w0 = half*256 + wv*64;

  bf16x8 wa[4][2];
  #pragma unroll
  for (int m=0;m<4;m++)
    #pragma unroll
    for (int ks=0;ks<2;ks++){
      B8 t; t.q = *(const uint4*)(wz + 3*4096 + (m*16+l15)*64 + ks*32 + l4*8);
      wa[m][ks] = t.v;
    }
  f32x4 dvv[4];
  #pragma unroll
  for (int m=0;m<4;m++) dvv[m] = *(const f32x4*)(dz + 3*64 + m*16 + l4*4);

  f32x4 acc[4][4];
  #pragma unroll
  for (int m=0;m<4;m++)
    #pragma unroll
    for (int n=0;n<4;n++) acc[m][n] = (f32x4){0.f,0.f,0.f,0.f};

  #pragma unroll
  for (int ks=0;ks<2;ks++){
    #pragma unroll
    for (int n=0;n<4;n++){
      B8 bb;
      #pragma unroll
      for (int jj=0;jj<4;jj++){
        int c0 = ks*32 + l4*8 + jj*2;
        size_t i0 = ((size_t)(b*64+c0)*512 + h)*512 + w0 + n*16 + l15;
        u32 lo = ob[i0], hi = ob[i0 + 262144];
        bb.u[jj] = lo | (hi << 16);
      }
      #pragma unroll
      for (int m=0;m<4;m++)
        acc[m][n] = MFMA16(wa[m][ks], bb.v, acc[m][n]);
    }
  }
  #pragma unroll
  for (int m=0;m<4;m++)
    #pragma unroll
    for (int n=0;n<4;n++)
      #pragma unroll
      for (int r=0;r<4;r++){
        int o = m*16 + l4*4 + r;
        size_t idx = ((size_t)(b*64+o)*512 + h)*512 + w0 + n*16 + l15;
        out[idx] = acc[m][n][r] + dvv[m][r] + f[idx];
      }
}

// ---------------- launch ----------------
extern "C" void kernel_launch(void* const* d_in, const int* in_sizes, int n_in,
                              void* d_out, int out_size, void* d_ws, size_t ws_size,
                              hipStream_t stream) {
  const float* feat = (const float*)d_in[0];
  char* ws = (char*)d_ws;
  // ws layout: [0,32K) bf16 weights (4x 64x64), [32K,33K) deltas (4x64 f32),
  // [64K..) three 128MiB bf16 buffers: bufQ (q -> P), bufK (k -> O), bufV (vT)
  // total required: 65536 + 3*134217728 = 402,718,720 bytes
  u16*   wz   = (u16*)ws;
  float* dz   = (float*)(ws + 32768);
  u16* bufQ = (u16*)(ws + 65536);
  u16* bufK = bufQ + 67108864ull;
  u16* bufV = bufK + 67108864ull;

  float extraK = 1.4426950408889634f / sqrtf(512.0f);  // fold 1/sqrt(W) * log2(e) into K
  for (int m=0; m<4; m++){
    int base = 1 + m*6;  // q:1..6, k:7..12, v:13..18, out:19..24
    float extra = (m==1) ? extraK : 1.0f;
    k0_prep<<<dim3(1), dim3(256), 0, stream>>>(
        (const float*)d_in[base+0], (const float*)d_in[base+1],
        (const float*)d_in[base+2], (const float*)d_in[base+3],
        (const float*)d_in[base+4], (const float*)d_in[base+5],
        extra, wz + m*4096, dz + m*64);
  }
  k1_qkv   <<<dim3(512),  dim3(256), 0, stream>>>(feat, wz, dz, bufQ, bufK, bufV);
  k2_scores<<<dim3(2048), dim3(256), 0, stream>>>(bufQ, bufK, bufQ);
  k3_pv    <<<dim3(2048), dim3(256), 0, stream>>>(bufQ, bufV, bufK);
  k4_out   <<<dim3(4096), dim3(256), 0, stream>>>(bufK, wz, dz, feat, (float*)d_out);
}

// Round 2
// 1040.547 us; speedup vs baseline: 1.0647x; 1.0647x over previous
//
#include <hip/hip_runtime.h>
#include <math.h>

typedef unsigned short u16;
typedef unsigned int u32;
typedef __attribute__((ext_vector_type(8))) short bf16x8;
typedef __attribute__((ext_vector_type(4))) float f32x4;

#define MFMA16(a,b,c) __builtin_amdgcn_mfma_f32_16x16x32_bf16(a,b,c,0,0,0)

__device__ __forceinline__ u16 f2bf(float x){
  union { float f; u32 u; } v; v.f = x;
  u32 u = v.u;
  return (u16)((u + 0x7fffu + ((u>>16)&1u)) >> 16);
}

union B8 { bf16x8 v; u32 u[4]; uint4 q; };

// ---------------- K0: fold BN into bf16 weights ----------------
__global__ void k0_prep(const float* wm, const float* bias, const float* gamma,
                        const float* beta, const float* mean, const float* var,
                        float extra, u16* wdst, float* ddst)
{
  int t = threadIdx.x;
  if (t < 64){
    float a0 = gamma[t] * rsqrtf(var[t] + 1e-5f);
    ddst[t] = (beta[t] + (bias[t] - mean[t]) * a0) * extra;
  }
  for (int i = t; i < 4096; i += 256){
    int o = i >> 6;
    float a0 = gamma[o] * rsqrtf(var[o] + 1e-5f);
    wdst[i] = f2bf(wm[i] * a0 * extra);
  }
}

// ---------------- K1: QKV projection + BN, writes q,k row-major and v transposed ----
__global__ __launch_bounds__(256,2)
void k1_qkv(const float* __restrict__ f, const u16* __restrict__ wz,
            const float* __restrict__ dz, u16* __restrict__ q,
            u16* __restrict__ kk_, u16* __restrict__ vt)
{
  int bid = blockIdx.x;
  int b  = bid >> 7;
  int ht = (bid >> 3) & 15;
  int wt = bid & 7;
  int tid = threadIdx.x;
  int wv = tid >> 6, lane = tid & 63;
  int l15 = lane & 15, l4 = lane >> 4;
  int h0 = ht * 32;
  int w0 = wt * 64 + wv * 16;

  bf16x8 wa[3][4][2];
  #pragma unroll
  for (int mt=0; mt<3; mt++)
    #pragma unroll
    for (int m=0;m<4;m++)
      #pragma unroll
      for (int ks=0;ks<2;ks++){
        B8 t; t.q = *(const uint4*)(wz + mt*4096 + (m*16+l15)*64 + ks*32 + l4*8);
        wa[mt][m][ks] = t.v;
      }
  f32x4 dv[3][4];
  #pragma unroll
  for (int mt=0;mt<3;mt++)
    #pragma unroll
    for (int m=0;m<4;m++)
      dv[mt][m] = *(const f32x4*)(dz + mt*64 + m*16 + l4*4);

  __shared__ u16 vstage[4][8704];
  u16* vs = vstage[wv];

  for (int hh=0; hh<32; hh++){
    int h = h0 + hh;
    B8 bf[2];
    #pragma unroll
    for (int ks=0;ks<2;ks++){
      #pragma unroll
      for (int jj=0;jj<4;jj++){
        int c0 = ks*32 + l4*8 + jj*2;
        size_t i0 = ((size_t)(b*64 + c0)*512 + h)*512 + w0 + l15;
        float x0 = f[i0];
        float x1 = f[i0 + 262144];
        bf[ks].u[jj] = (u32)f2bf(x0) | ((u32)f2bf(x1) << 16);
      }
    }
    #pragma unroll
    for (int mt=0; mt<3; mt++){
      f32x4 acc[4];
      #pragma unroll
      for (int m=0;m<4;m++) acc[m] = (f32x4){0.f,0.f,0.f,0.f};
      #pragma unroll
      for (int m=0;m<4;m++)
        #pragma unroll
        for (int ks=0;ks<2;ks++)
          acc[m] = MFMA16(wa[mt][m][ks], bf[ks].v, acc[m]);
      #pragma unroll
      for (int m=0;m<4;m++)
        #pragma unroll
        for (int r=0;r<4;r++){
          float val = acc[m][r] + dv[mt][m][r];
          u16 bv = f2bf(val);
          int o = m*16 + l4*4 + r;
          if (mt==0)      q  [((size_t)(b*64+o)*512 + h)*512 + w0 + l15] = bv;
          else if (mt==1) kk_[((size_t)(b*64+o)*512 + h)*512 + w0 + l15] = bv;
          else            vs[o*136 + l15*8 + (hh&7)] = bv;
        }
    }
    if ((hh&7)==7){
      __syncthreads();
      int hb = h - 7;
      #pragma unroll
      for (int r=0;r<16;r++){
        int o = r*4 + l4;
        uint4 d = *(const uint4*)(vs + o*136 + l15*8);
        *(uint4*)(vt + ((size_t)(b*64+o)*512 + (w0+l15))*512 + hb) = d;
      }
      __syncthreads();
    }
  }
}

// ---------------- K23: fused flash attention per (head, 128-row q-tile) ----------
// grid 1024, 512 threads (8 waves). LDS: K-tile 64KB + V^T-tile 64KB + P 16KB + fac.
// S-role: wave wv owns q-rows [wv*16, +16) -> full in-wave softmax (online).
// PV-role: wave (mr=wv>>1, nc=wv&1) owns O[mr*32..+32][nc*256..+256].
// O written in-place over this block's own Q rows (exclusive ownership).
__global__ __launch_bounds__(512,2)
void k23_attn(const u16* q, const u16* __restrict__ kten,
              const u16* __restrict__ vt, u16* o)
{
  int phys = blockIdx.x;
  int x = phys & 7, j = phys >> 3;
  int qt = j & 3, hh = j >> 2;
  int head = x*32 + hh;          // XCD x handles heads x*32..x*32+31 consecutively
  int q0 = qt*128;

  int tid = threadIdx.x;
  int wv = tid >> 6, lane = tid & 63;
  int l15 = lane & 15, l4 = lane >> 4;
  int mr = wv >> 1, nc = wv & 1;

  const u16* qh = q    + (size_t)head*262144;
  const u16* kh = kten + (size_t)head*262144;
  const u16* vh = vt   + (size_t)head*262144;   // vh[w*512+g] = V[g][w]

  __shared__ u16 Kt[64*512];     // [g][w], 16B chunks XOR-swizzled by (g&7)
  __shared__ u16 Vt[512*64];     // [w][g], chunks XOR-swizzled by (w&7)
  __shared__ u16 Pt[128*64];     // [q][g] bf16, elems XOR-swizzled by (q&7)<<3
  __shared__ float facb[128];

  f32x4 oacc[2][16];
  #pragma unroll
  for (int mt=0;mt<2;mt++)
    #pragma unroll
    for (int n=0;n<16;n++) oacc[mt][n] = (f32x4){0.f,0.f,0.f,0.f};
  float m_run[4] = {-1e30f,-1e30f,-1e30f,-1e30f};
  float l_run[4] = {0.f,0.f,0.f,0.f};
  float facr[4];

  const u16* qrow = qh + (size_t)(q0 + wv*16 + l15)*512;

  for (int gt=0; gt<8; ++gt){
    // ---- stage K[gt] (rows g, swizzled chunks) and V^T[gt] ----
    #pragma unroll
    for (int p=0;p<8;p++){
      int g = p*8 + wv;
      uint4 d = *(const uint4*)(kh + (size_t)(gt*64+g)*512 + ((lane ^ (g&7))<<3));
      *(uint4*)(Kt + g*512 + lane*8) = d;
    }
    #pragma unroll
    for (int p=0;p<8;p++){
      int w = p*64 + wv*8 + (lane>>3);
      int c = lane & 7;
      uint4 d = *(const uint4*)(vh + (size_t)w*512 + gt*64 + ((c ^ (w&7))<<3));
      *(uint4*)(Vt + w*64 + c*8) = d;
    }
    __syncthreads();

    // ---- S = Q K^T for my 16 rows x 64 g (scale*log2e folded into K weights) ----
    f32x4 sacc[4];
    #pragma unroll
    for (int n=0;n<4;n++) sacc[n] = (f32x4){0.f,0.f,0.f,0.f};
    #pragma unroll
    for (int ks=0; ks<16; ++ks){
      B8 a; a.q = *(const uint4*)(qrow + ks*32 + l4*8);
      #pragma unroll
      for (int n=0;n<4;n++){
        int g = n*16 + l15;
        B8 b; b.q = *(const uint4*)(Kt + g*512 + (((ks*4+l4) ^ (g&7))<<3));
        sacc[n] = MFMA16(a.v, b.v, sacc[n]);
      }
    }

    // ---- in-wave online softmax (rows = wv*16 + l4*4 + r) ----
    #pragma unroll
    for (int r=0;r<4;r++){
      float pm = fmaxf(fmaxf(sacc[0][r],sacc[1][r]), fmaxf(sacc[2][r],sacc[3][r]));
      #pragma unroll
      for (int d=1; d<16; d<<=1) pm = fmaxf(pm, __shfl_xor(pm, d, 64));
      float mn = fmaxf(m_run[r], pm);
      float fc = exp2f(m_run[r] - mn);
      m_run[r] = mn;
      float s = 0.f;
      #pragma unroll
      for (int n=0;n<4;n++){ float e = exp2f(sacc[n][r] - mn); sacc[n][r] = e; s += e; }
      #pragma unroll
      for (int d=1; d<16; d<<=1) s += __shfl_xor(s, d, 64);
      l_run[r] = l_run[r]*fc + s;
      facr[r] = fc;
    }
    if (l15 == 0){
      #pragma unroll
      for (int r=0;r<4;r++) facb[wv*16 + l4*4 + r] = facr[r];
    }
    #pragma unroll
    for (int n=0;n<4;n++)
      #pragma unroll
      for (int r=0;r<4;r++){
        int qq = wv*16 + l4*4 + r;
        int g = n*16 + l15;
        Pt[qq*64 + (g ^ ((qq&7)<<3))] = f2bf(sacc[n][r]);
      }
    __syncthreads();

    // ---- PV: O[mr*32..+32][nc*256..+256] += P * V ----
    #pragma unroll
    for (int mt=0;mt<2;mt++)
      #pragma unroll
      for (int r=0;r<4;r++){
        float fc = facb[mr*32 + mt*16 + l4*4 + r];
        #pragma unroll
        for (int n=0;n<16;n++) oacc[mt][n][r] *= fc;
      }
    #pragma unroll
    for (int kg=0;kg<2;kg++){
      B8 a0, a1;
      { int qq = mr*32 + l15;        a0.q = *(const uint4*)(Pt + qq*64 + (((kg*4+l4) ^ (qq&7))<<3)); }
      { int qq = mr*32 + 16 + l15;   a1.q = *(const uint4*)(Pt + qq*64 + (((kg*4+l4) ^ (qq&7))<<3)); }
      #pragma unroll
      for (int n=0;n<16;n++){
        int w = nc*256 + n*16 + l15;
        B8 b; b.q = *(const uint4*)(Vt + w*64 + (((kg*4+l4) ^ (w&7))<<3));
        oacc[0][n] = MFMA16(a0.v, b.v, oacc[0][n]);
        oacc[1][n] = MFMA16(a1.v, b.v, oacc[1][n]);
      }
    }
    __syncthreads();
  }

  // ---- publish 1/l, then write O over own Q rows ----
  if (l15 == 0){
    #pragma unroll
    for (int r=0;r<4;r++) facb[wv*16 + l4*4 + r] = 1.0f / l_run[r];
  }
  __syncthreads();
  u16* oh = o + (size_t)head*262144;
  #pragma unroll
  for (int mt=0;mt<2;mt++)
    #pragma unroll
    for (int r=0;r<4;r++){
      float li = facb[mr*32 + mt*16 + l4*4 + r];
      int qq = q0 + mr*32 + mt*16 + l4*4 + r;
      #pragma unroll
      for (int n=0;n<16;n++){
        int w = nc*256 + n*16 + l15;
        oh[(size_t)qq*512 + w] = f2bf(oacc[mt][n][r]*li);
      }
    }
}

// ---------------- K4: out conv + BN + residual, fp32 out ----------------
__global__ __launch_bounds__(256,2)
void k4_out(const u16* __restrict__ ob, const u16* __restrict__ wz,
            const float* __restrict__ dz, const float* __restrict__ f,
            float* __restrict__ out)
{
  int bid = blockIdx.x;
  int b = bid >> 10;
  int h = (bid >> 1) & 511;
  int half = bid & 1;
  int tid = threadIdx.x, wv = tid>>6, lane = tid&63;
  int l15 = lane&15, l4 = lane>>4;
  int w0 = half*256 + wv*64;

  bf16x8 wa[4][2];
  #pragma unroll
  for (int m=0;m<4;m++)
    #pragma unroll
    for (int ks=0;ks<2;ks++){
      B8 t; t.q = *(const uint4*)(wz + 3*4096 + (m*16+l15)*64 + ks*32 + l4*8);
      wa[m][ks] = t.v;
    }
  f32x4 dvv[4];
  #pragma unroll
  for (int m=0;m<4;m++) dvv[m] = *(const f32x4*)(dz + 3*64 + m*16 + l4*4);

  f32x4 acc[4][4];
  #pragma unroll
  for (int m=0;m<4;m++)
    #pragma unroll
    for (int n=0;n<4;n++) acc[m][n] = (f32x4){0.f,0.f,0.f,0.f};

  #pragma unroll
  for (int ks=0;ks<2;ks++){
    #pragma unroll
    for (int n=0;n<4;n++){
      B8 bb;
      #pragma unroll
      for (int jj=0;jj<4;jj++){
        int c0 = ks*32 + l4*8 + jj*2;
        size_t i0 = ((size_t)(b*64+c0)*512 + h)*512 + w0 + n*16 + l15;
        u32 lo = ob[i0], hi = ob[i0 + 262144];
        bb.u[jj] = lo | (hi << 16);
      }
      #pragma unroll
      for (int m=0;m<4;m++)
        acc[m][n] = MFMA16(wa[m][ks], bb.v, acc[m][n]);
    }
  }
  #pragma unroll
  for (int m=0;m<4;m++)
    #pragma unroll
    for (int n=0;n<4;n++)
      #pragma unroll
      for (int r=0;r<4;r++){
        int o = m*16 + l4*4 + r;
        size_t idx = ((size_t)(b*64+o)*512 + h)*512 + w0 + n*16 + l15;
        out[idx] = acc[m][n][r] + dvv[m][r] + f[idx];
      }
}

// ---------------- launch ----------------
extern "C" void kernel_launch(void* const* d_in, const int* in_sizes, int n_in,
                              void* d_out, int out_size, void* d_ws, size_t ws_size,
                              hipStream_t stream) {
  const float* feat = (const float*)d_in[0];
  char* ws = (char*)d_ws;
  u16*   wz   = (u16*)ws;
  float* dz   = (float*)(ws + 32768);
  u16* bufQ = (u16*)(ws + 65536);     // q -> O (in-place per-block)
  u16* bufK = bufQ + 67108864ull;     // k
  u16* bufV = bufK + 67108864ull;     // vT

  float extraK = 1.4426950408889634f / sqrtf(512.0f);  // fold 1/sqrt(W)*log2(e) into K
  for (int m=0; m<4; m++){
    int base = 1 + m*6;
    float extra = (m==1) ? extraK : 1.0f;
    k0_prep<<<dim3(1), dim3(256), 0, stream>>>(
        (const float*)d_in[base+0], (const float*)d_in[base+1],
        (const float*)d_in[base+2], (const float*)d_in[base+3],
        (const float*)d_in[base+4], (const float*)d_in[base+5],
        extra, wz + m*4096, dz + m*64);
  }
  k1_qkv   <<<dim3(512),  dim3(256), 0, stream>>>(feat, wz, dz, bufQ, bufK, bufV);
  k23_attn <<<dim3(1024), dim3(512), 0, stream>>>(bufQ, bufK, bufV, bufQ);
  k4_out   <<<dim3(4096), dim3(256), 0, stream>>>(bufQ, wz, dz, feat, (float*)d_out);
}

// Round 3
// 894.546 us; speedup vs baseline: 1.2384x; 1.1632x over previous
//
#include <hip/hip_runtime.h>
#include <math.h>

typedef unsigned short u16;
typedef unsigned int u32;
typedef __attribute__((ext_vector_type(8))) short bf16x8;
typedef __attribute__((ext_vector_type(4))) float f32x4;

#define MFMA16(a,b,c) __builtin_amdgcn_mfma_f32_16x16x32_bf16(a,b,c,0,0,0)

typedef __attribute__((address_space(1))) const unsigned int as1_u32;
typedef __attribute__((address_space(3))) unsigned int as3_u32;
__device__ __forceinline__ void gld16(const u16* g, u16* l){
  __builtin_amdgcn_global_load_lds((as1_u32*)g, (as3_u32*)l, 16, 0, 0);
}

__device__ __forceinline__ u16 f2bf(float x){
  union { float f; u32 u; } v; v.f = x;
  u32 u = v.u;
  return (u16)((u + 0x7fffu + ((u>>16)&1u)) >> 16);
}

union B8 { bf16x8 v; u32 u[4]; uint4 q; };

// ---------------- K0: fold BN into bf16 weights ----------------
__global__ void k0_prep(const float* wm, const float* bias, const float* gamma,
                        const float* beta, const float* mean, const float* var,
                        float extra, u16* wdst, float* ddst)
{
  int t = threadIdx.x;
  if (t < 64){
    float a0 = gamma[t] * rsqrtf(var[t] + 1e-5f);
    ddst[t] = (beta[t] + (bias[t] - mean[t]) * a0) * extra;
  }
  for (int i = t; i < 4096; i += 256){
    int o = i >> 6;
    float a0 = gamma[o] * rsqrtf(var[o] + 1e-5f);
    wdst[i] = f2bf(wm[i] * a0 * extra);
  }
}

// ---------------- K1: QKV projection + BN, writes q,k row-major and v transposed ----
__global__ __launch_bounds__(256,2)
void k1_qkv(const float* __restrict__ f, const u16* __restrict__ wz,
            const float* __restrict__ dz, u16* __restrict__ q,
            u16* __restrict__ kk_, u16* __restrict__ vt)
{
  int bid = blockIdx.x;
  int b  = bid >> 7;
  int ht = (bid >> 3) & 15;
  int wt = bid & 7;
  int tid = threadIdx.x;
  int wv = tid >> 6, lane = tid & 63;
  int l15 = lane & 15, l4 = lane >> 4;
  int h0 = ht * 32;
  int w0 = wt * 64 + wv * 16;

  bf16x8 wa[3][4][2];
  #pragma unroll
  for (int mt=0; mt<3; mt++)
    #pragma unroll
    for (int m=0;m<4;m++)
      #pragma unroll
      for (int ks=0;ks<2;ks++){
        B8 t; t.q = *(const uint4*)(wz + mt*4096 + (m*16+l15)*64 + ks*32 + l4*8);
        wa[mt][m][ks] = t.v;
      }
  f32x4 dv[3][4];
  #pragma unroll
  for (int mt=0;mt<3;mt++)
    #pragma unroll
    for (int m=0;m<4;m++)
      dv[mt][m] = *(const f32x4*)(dz + mt*64 + m*16 + l4*4);

  __shared__ u16 vstage[4][8704];
  u16* vs = vstage[wv];

  for (int hh=0; hh<32; hh++){
    int h = h0 + hh;
    B8 bf[2];
    #pragma unroll
    for (int ks=0;ks<2;ks++){
      #pragma unroll
      for (int jj=0;jj<4;jj++){
        int c0 = ks*32 + l4*8 + jj*2;
        size_t i0 = ((size_t)(b*64 + c0)*512 + h)*512 + w0 + l15;
        float x0 = f[i0];
        float x1 = f[i0 + 262144];
        bf[ks].u[jj] = (u32)f2bf(x0) | ((u32)f2bf(x1) << 16);
      }
    }
    #pragma unroll
    for (int mt=0; mt<3; mt++){
      f32x4 acc[4];
      #pragma unroll
      for (int m=0;m<4;m++) acc[m] = (f32x4){0.f,0.f,0.f,0.f};
      #pragma unroll
      for (int m=0;m<4;m++)
        #pragma unroll
        for (int ks=0;ks<2;ks++)
          acc[m] = MFMA16(wa[mt][m][ks], bf[ks].v, acc[m]);
      #pragma unroll
      for (int m=0;m<4;m++)
        #pragma unroll
        for (int r=0;r<4;r++){
          float val = acc[m][r] + dv[mt][m][r];
          u16 bv = f2bf(val);
          int o = m*16 + l4*4 + r;
          if (mt==0)      q  [((size_t)(b*64+o)*512 + h)*512 + w0 + l15] = bv;
          else if (mt==1) kk_[((size_t)(b*64+o)*512 + h)*512 + w0 + l15] = bv;
          else            vs[o*136 + l15*8 + (hh&7)] = bv;
        }
    }
    if ((hh&7)==7){
      __syncthreads();
      int hb = h - 7;
      #pragma unroll
      for (int r=0;r<16;r++){
        int o = r*4 + l4;
        uint4 d = *(const uint4*)(vs + o*136 + l15*8);
        *(uint4*)(vt + ((size_t)(b*64+o)*512 + (w0+l15))*512 + hb) = d;
      }
      __syncthreads();
    }
  }
}

// ---------------- K23 v2: flash attention, counted-vmcnt pipeline ----------------
// grid 1024, 512 thr (8 waves). Q-tile 128 rows, KVBLK 32 (16 g-tiles).
// K/V double-buffered in LDS via global_load_lds(16B), source-addr swizzled (T21).
// Loop never drains vmcnt to 0; raw s_barrier + counted vmcnt(8) keep 1 tile in flight.
__global__ __launch_bounds__(512,2)
void k23_attn(const u16* __restrict__ q, const u16* __restrict__ kten,
              const u16* __restrict__ vt, u16* __restrict__ o)
{
  int phys = blockIdx.x;
  int x = phys & 7, j = phys >> 3;
  int qt = j & 3, hh = j >> 2;
  int head = x*32 + hh;          // XCD x -> heads x*32.., 4 q-tiles of a head adjacent
  int q0 = qt*128;

  int tid = threadIdx.x;
  int wv = tid >> 6, lane = tid & 63;
  int l15 = lane & 15, l4 = lane >> 4;
  int mr = wv >> 1, nc = wv & 1;

  const u16* qh = q    + (size_t)head*262144;
  const u16* kh = kten + (size_t)head*262144;
  const u16* vh = vt   + (size_t)head*262144;   // vh[w*512+g] = V[g][w]

  __shared__ u16 KB[2][16384];   // [32 g][512 w]; chunk slot c holds global chunk c^(g&7)
  __shared__ u16 VB[2][16384];   // [512 w][32 g]; chunk slot c holds global chunk c^(w&3)
  __shared__ u16 Pt[8192];       // [128 q][64]; col-chunk (g>>3) stored at slot (g>>3)^(q&7)
  __shared__ float facb[128];

  // stage one K+V g-tile into buffer `buf` (8 x 16B global_load_lds per thread)
  auto stage = [&](int gts, int buf){
    const u16* ksrc = kh + (size_t)gts*16384;
    #pragma unroll
    for (int i=0;i<4;i++){
      int g = i*8 + wv;
      gld16(ksrc + (size_t)g*512 + ((lane ^ (g&7))<<3), &KB[buf][i*4096 + tid*8]);
    }
    const u16* vsrc = vh + gts*32;
    #pragma unroll
    for (int i=0;i<4;i++){
      int w = i*128 + (tid>>2);
      int c = tid & 3;
      gld16(vsrc + (size_t)w*512 + ((c ^ (w&3))<<3), &VB[buf][i*4096 + tid*8]);
    }
  };

  f32x4 oacc[2][16];
  #pragma unroll
  for (int mt=0;mt<2;mt++)
    #pragma unroll
    for (int n=0;n<16;n++) oacc[mt][n] = (f32x4){0.f,0.f,0.f,0.f};
  float m_run[4] = {-1e30f,-1e30f,-1e30f,-1e30f};
  float l_run[4] = {0.f,0.f,0.f,0.f};

  // prologue: issue tile0, Q->regs, tile1; wait tile0 (tile1 stays in flight)
  stage(0, 0);
  uint4 qreg[16];
  {
    const u16* qrow = qh + (size_t)(q0 + wv*16 + l15)*512;
    #pragma unroll
    for (int ks=0;ks<16;ks++) qreg[ks] = *(const uint4*)(qrow + ks*32 + l4*8);
  }
  stage(1, 1);
  asm volatile("s_waitcnt vmcnt(8)" ::: "memory");
  __builtin_amdgcn_s_barrier();

  for (int gt=0; gt<16; ++gt){
    int cur = gt & 1;
    const u16* Kc = &KB[cur][0];
    const u16* Vc = &VB[cur][0];

    // ---- S = Q K^T for my 16 rows x 32 g ----
    f32x4 sacc[2];
    sacc[0] = (f32x4){0.f,0.f,0.f,0.f};
    sacc[1] = (f32x4){0.f,0.f,0.f,0.f};
    __builtin_amdgcn_s_setprio(1);
    #pragma unroll
    for (int ks=0; ks<16; ++ks){
      B8 a; a.q = qreg[ks];
      #pragma unroll
      for (int n=0;n<2;n++){
        int g = n*16 + l15;
        B8 b; b.q = *(const uint4*)(Kc + g*512 + (((ks*4+l4) ^ (g&7))<<3));
        sacc[n] = MFMA16(a.v, b.v, sacc[n]);
      }
    }
    __builtin_amdgcn_s_setprio(0);

    // ---- online softmax with defer-max (THR=4) ----
    float pm[4], fc[4];
    bool need = false;
    #pragma unroll
    for (int r=0;r<4;r++){
      float p = fmaxf(sacc[0][r], sacc[1][r]);
      #pragma unroll
      for (int d=1; d<16; d<<=1) p = fmaxf(p, __shfl_xor(p, d, 64));
      pm[r] = p;
      need = need || (p > m_run[r] + 4.0f);
    }
    if (__any(need ? 1 : 0)){
      #pragma unroll
      for (int r=0;r<4;r++){
        float mn = fmaxf(m_run[r], pm[r]);
        fc[r] = exp2f(m_run[r] - mn);
        m_run[r] = mn;
      }
    } else {
      fc[0]=fc[1]=fc[2]=fc[3]=1.0f;
    }
    #pragma unroll
    for (int r=0;r<4;r++){
      float e0 = exp2f(sacc[0][r] - m_run[r]);
      float e1 = exp2f(sacc[1][r] - m_run[r]);
      sacc[0][r] = e0; sacc[1][r] = e1;
      float s = e0 + e1;
      #pragma unroll
      for (int d=1; d<16; d<<=1) s += __shfl_xor(s, d, 64);
      l_run[r] = l_run[r]*fc[r] + s;
    }
    if (l15 == 0){
      #pragma unroll
      for (int r=0;r<4;r++) facb[wv*16 + l4*4 + r] = fc[r];
    }
    #pragma unroll
    for (int n=0;n<2;n++)
      #pragma unroll
      for (int r=0;r<4;r++){
        int qq = wv*16 + l4*4 + r;
        int cc = (n*2 + (l15>>3)) ^ (qq&7);
        Pt[qq*64 + (cc<<3) + (l15&7)] = f2bf(sacc[n][r]);
      }
    asm volatile("s_waitcnt lgkmcnt(0)" ::: "memory");
    __builtin_amdgcn_s_barrier();           // Pt + facb visible to all waves

    // ---- PV: O[mr*32..+32][nc*256..+256] += P * V ----
    float fr[8]; bool needm = false;
    #pragma unroll
    for (int mt=0;mt<2;mt++)
      #pragma unroll
      for (int r=0;r<4;r++){
        float f_ = facb[mr*32 + mt*16 + l4*4 + r];
        fr[mt*4+r] = f_;
        needm = needm || (f_ != 1.0f);
      }
    if (__any(needm ? 1 : 0)){
      #pragma unroll
      for (int mt=0;mt<2;mt++)
        #pragma unroll
        for (int r=0;r<4;r++){
          float f_ = fr[mt*4+r];
          #pragma unroll
          for (int n=0;n<16;n++) oacc[mt][n][r] *= f_;
        }
    }
    B8 a0, a1;
    { int qq = mr*32 + l15;      a0.q = *(const uint4*)(Pt + qq*64 + ((l4 ^ (qq&7))<<3)); }
    { int qq = mr*32 + 16 + l15; a1.q = *(const uint4*)(Pt + qq*64 + ((l4 ^ (qq&7))<<3)); }
    __builtin_amdgcn_s_setprio(1);
    #pragma unroll
    for (int n=0;n<16;n++){
      int w = nc*256 + n*16 + l15;
      B8 b; b.q = *(const uint4*)(Vc + w*32 + ((l4 ^ (w&3))<<3));
      oacc[0][n] = MFMA16(a0.v, b.v, oacc[0][n]);
      oacc[1][n] = MFMA16(a1.v, b.v, oacc[1][n]);
    }
    __builtin_amdgcn_s_setprio(0);

    // ---- pipeline control: refill buf[cur] for gt+2 ----
    if (gt < 15){
      asm volatile("" ::: "memory");
      __builtin_amdgcn_s_barrier();         // all waves done reading buf[cur] + Pt
      if (gt < 14){
        stage(gt+2, cur);
        asm volatile("s_waitcnt vmcnt(8)" ::: "memory");   // gt+1's loads landed
      } else {
        asm volatile("s_waitcnt vmcnt(0)" ::: "memory");   // last tile: drain
      }
      __builtin_amdgcn_s_barrier();         // buf[gt+1] ready for all
    }
  }

  // ---- epilogue: publish 1/l, write O over own Q rows ----
  __syncthreads();
  if (l15 == 0){
    #pragma unroll
    for (int r=0;r<4;r++) facb[wv*16 + l4*4 + r] = 1.0f / l_run[r];
  }
  __syncthreads();
  u16* oh = o + (size_t)head*262144;
  #pragma unroll
  for (int mt=0;mt<2;mt++)
    #pragma unroll
    for (int r=0;r<4;r++){
      float li = facb[mr*32 + mt*16 + l4*4 + r];
      int qq = q0 + mr*32 + mt*16 + l4*4 + r;
      #pragma unroll
      for (int n=0;n<16;n++){
        int w = nc*256 + n*16 + l15;
        oh[(size_t)qq*512 + w] = f2bf(oacc[mt][n][r]*li);
      }
    }
}

// ---------------- K4: out conv + BN + residual, fp32 out ----------------
__global__ __launch_bounds__(256,2)
void k4_out(const u16* __restrict__ ob, const u16* __restrict__ wz,
            const float* __restrict__ dz, const float* __restrict__ f,
            float* __restrict__ out)
{
  int bid = blockIdx.x;
  int b = bid >> 10;
  int h = (bid >> 1) & 511;
  int half = bid & 1;
  int tid = threadIdx.x, wv = tid>>6, lane = tid&63;
  int l15 = lane&15, l4 = lane>>4;
  int w0 = half*256 + wv*64;

  bf16x8 wa[4][2];
  #pragma unroll
  for (int m=0;m<4;m++)
    #pragma unroll
    for (int ks=0;ks<2;ks++){
      B8 t; t.q = *(const uint4*)(wz + 3*4096 + (m*16+l15)*64 + ks*32 + l4*8);
      wa[m][ks] = t.v;
    }
  f32x4 dvv[4];
  #pragma unroll
  for (int m=0;m<4;m++) dvv[m] = *(const f32x4*)(dz + 3*64 + m*16 + l4*4);

  f32x4 acc[4][4];
  #pragma unroll
  for (int m=0;m<4;m++)
    #pragma unroll
    for (int n=0;n<4;n++) acc[m][n] = (f32x4){0.f,0.f,0.f,0.f};

  #pragma unroll
  for (int ks=0;ks<2;ks++){
    #pragma unroll
    for (int n=0;n<4;n++){
      B8 bb;
      #pragma unroll
      for (int jj=0;jj<4;jj++){
        int c0 = ks*32 + l4*8 + jj*2;
        size_t i0 = ((size_t)(b*64+c0)*512 + h)*512 + w0 + n*16 + l15;
        u32 lo = ob[i0], hi = ob[i0 + 262144];
        bb.u[jj] = lo | (hi << 16);
      }
      #pragma unroll
      for (int m=0;m<4;m++)
        acc[m][n] = MFMA16(wa[m][ks], bb.v, acc[m][n]);
    }
  }
  #pragma unroll
  for (int m=0;m<4;m++)
    #pragma unroll
    for (int n=0;n<4;n++)
      #pragma unroll
      for (int r=0;r<4;r++){
        int o = m*16 + l4*4 + r;
        size_t idx = ((size_t)(b*64+o)*512 + h)*512 + w0 + n*16 + l15;
        out[idx] = acc[m][n][r] + dvv[m][r] + f[idx];
      }
}

// ---------------- launch ----------------
extern "C" void kernel_launch(void* const* d_in, const int* in_sizes, int n_in,
                              void* d_out, int out_size, void* d_ws, size_t ws_size,
                              hipStream_t stream) {
  const float* feat = (const float*)d_in[0];
  char* ws = (char*)d_ws;
  u16*   wz   = (u16*)ws;
  float* dz   = (float*)(ws + 32768);
  u16* bufQ = (u16*)(ws + 65536);     // q -> O (in-place per-block)
  u16* bufK = bufQ + 67108864ull;     // k
  u16* bufV = bufK + 67108864ull;     // vT

  float extraK = 1.4426950408889634f / sqrtf(512.0f);  // fold 1/sqrt(W)*log2(e) into K
  for (int m=0; m<4; m++){
    int base = 1 + m*6;
    float extra = (m==1) ? extraK : 1.0f;
    k0_prep<<<dim3(1), dim3(256), 0, stream>>>(
        (const float*)d_in[base+0], (const float*)d_in[base+1],
        (const float*)d_in[base+2], (const float*)d_in[base+3],
        (const float*)d_in[base+4], (const float*)d_in[base+5],
        extra, wz + m*4096, dz + m*64);
  }
  k1_qkv   <<<dim3(512),  dim3(256), 0, stream>>>(feat, wz, dz, bufQ, bufK, bufV);
  k23_attn <<<dim3(1024), dim3(512), 0, stream>>>(bufQ, bufK, bufV, bufQ);
  k4_out   <<<dim3(4096), dim3(256), 0, stream>>>(bufQ, wz, dz, feat, (float*)d_out);
}